// Round 9
// baseline (149.551 us; speedup 1.0000x reference)
//
#include <hip/hip_runtime.h>

#define N_NODES 4096
#define E_EDGES 131072
#define IN_F    256
#define OUT_F   64
#define HEADS   4
#define HC      256        // HEADS*OUT_F
#define CAP     128        // per-row slot capacity (fixed dataset degree: mean 32, max ~54)

typedef float v4f __attribute__((ext_vector_type(4)));
typedef short v8s __attribute__((ext_vector_type(8)));   // 8 bf16 (4 VGPRs) MFMA A/B fragment
typedef float v4acc __attribute__((ext_vector_type(4))); // MFMA C/D fragment

__device__ __forceinline__ unsigned short bf16_rn(float x) {
    unsigned u = __builtin_bit_cast(unsigned, x);
    unsigned r = (u + 0x7FFFu + ((u >> 16) & 1u)) >> 16;   // round-to-nearest-even
    return (unsigned short)r;
}
__device__ __forceinline__ float bf16_to_f(unsigned short b) {
    unsigned u = ((unsigned)b) << 16;
    return __builtin_bit_cast(float, u);
}

// ---------------- K0: split h,W into bf16 hi/lo (x4 vectorized) + zero rowcnt/S ----------------
__global__ __launch_bounds__(256) void k_prep(
        const float* __restrict__ h, const float* __restrict__ W,
        unsigned short* __restrict__ h_hi, unsigned short* __restrict__ h_lo,
        unsigned short* __restrict__ W_hi, unsigned short* __restrict__ W_lo,
        int* __restrict__ rowcnt, float* __restrict__ S) {
    const int tid = blockIdx.x * 256 + threadIdx.x;
    if (tid < N_NODES) rowcnt[tid] = 0;
    else if (tid < N_NODES + HC) S[tid - N_NODES] = 0.f;

    const int HN4 = (N_NODES * IN_F) / 4;     // 262144
    const float4* src;
    unsigned short *dhi, *dlo;
    int j;
    if (tid < HN4) { src = (const float4*)h; dhi = h_hi; dlo = h_lo; j = tid; }
    else           { src = (const float4*)W; dhi = W_hi; dlo = W_lo; j = tid - HN4; }
    const float4 x = src[j];
    const unsigned short hx = bf16_rn(x.x), hy = bf16_rn(x.y), hz = bf16_rn(x.z), hw = bf16_rn(x.w);
    ushort4 hi4 = make_ushort4(hx, hy, hz, hw);
    ushort4 lo4 = make_ushort4(bf16_rn(x.x - bf16_to_f(hx)), bf16_rn(x.y - bf16_to_f(hy)),
                               bf16_rn(x.z - bf16_to_f(hz)), bf16_rn(x.w - bf16_to_f(hw)));
    *(ushort4*)(dhi + j * 4) = hi4;
    *(ushort4*)(dlo + j * 4) = lo4;
}

// ---------------- K1: edge append + Wh = h @ W^T via split bf16 MFMA + s1/s2/colsum ----------------
__global__ __launch_bounds__(256) void k_linear_mfma(
        const unsigned short* __restrict__ h_hi, const unsigned short* __restrict__ h_lo,
        const unsigned short* __restrict__ W_hi, const unsigned short* __restrict__ W_lo,
        const float* __restrict__ a, const int* __restrict__ rows,
        int* __restrict__ rowcnt, int* __restrict__ slots,
        float* __restrict__ Wh, float* __restrict__ s1, float* __restrict__ s2,
        float* __restrict__ S) {
    const int t = threadIdx.x;

    // --- edge append (independent of MFMA dataflow; hides under A/B load latency) ---
    {
        const int e0 = blockIdx.x * 512 + t;
#pragma unroll
        for (int rep = 0; rep < 2; ++rep) {
            const int k = e0 + rep * 256;
            const int r = rows[k];
            const int pos = atomicAdd(&rowcnt[r], 1);
            if (pos < CAP) slots[r * CAP + pos] = k;
        }
    }

    const int wave = t >> 6, lane = t & 63;
    const int n16 = lane & 15, quad = lane >> 4;
    const int node0 = blockIdx.x * 16;
    const int ch0 = wave * 64;
    const int head = wave;

    v4acc acc[4];
#pragma unroll
    for (int nt = 0; nt < 4; ++nt) acc[nt] = (v4acc){0.f, 0.f, 0.f, 0.f};

    const int arow = (node0 + n16) * IN_F;
#pragma unroll
    for (int s = 0; s < 8; ++s) {                       // K = 256 in steps of 32
        const int k0 = s * 32 + quad * 8;
        v8s Ah = *(const v8s*)(h_hi + arow + k0);
        v8s Al = *(const v8s*)(h_lo + arow + k0);
#pragma unroll
        for (int nt = 0; nt < 4; ++nt) {
            const int ch = ch0 + nt * 16 + n16;
            v8s Bh = *(const v8s*)(W_hi + ch * IN_F + k0);
            v8s Bl = *(const v8s*)(W_lo + ch * IN_F + k0);
            acc[nt] = __builtin_amdgcn_mfma_f32_16x16x32_bf16(Ah, Bh, acc[nt], 0, 0, 0);
            acc[nt] = __builtin_amdgcn_mfma_f32_16x16x32_bf16(Ah, Bl, acc[nt], 0, 0, 0);
            acc[nt] = __builtin_amdgcn_mfma_f32_16x16x32_bf16(Al, Bh, acc[nt], 0, 0, 0);
        }
    }

#pragma unroll
    for (int nt = 0; nt < 4; ++nt) {
        const int ch = ch0 + nt * 16 + n16;
#pragma unroll
        for (int r = 0; r < 4; ++r)
            Wh[(size_t)(node0 + quad * 4 + r) * HC + ch] = acc[nt][r];
    }

    float a1v[4], a2v[4];
#pragma unroll
    for (int nt = 0; nt < 4; ++nt) {
        a1v[nt] = a[head * 2 * OUT_F + nt * 16 + n16];
        a2v[nt] = a[head * 2 * OUT_F + OUT_F + nt * 16 + n16];
    }
#pragma unroll
    for (int r = 0; r < 4; ++r) {
        float p1 = acc[0][r] * a1v[0] + acc[1][r] * a1v[1] + acc[2][r] * a1v[2] + acc[3][r] * a1v[3];
        float p2 = acc[0][r] * a2v[0] + acc[1][r] * a2v[1] + acc[2][r] * a2v[2] + acc[3][r] * a2v[3];
#pragma unroll
        for (int o = 1; o < 16; o <<= 1) {
            p1 += __shfl_xor(p1, o, 64);
            p2 += __shfl_xor(p2, o, 64);
        }
        if (n16 == 0) {
            const int node = node0 + quad * 4 + r;
            s1[node * HEADS + head] = p1;
            s2[node * HEADS + head] = p2;
        }
    }

#pragma unroll
    for (int nt = 0; nt < 4; ++nt) {
        float cp = acc[nt][0] + acc[nt][1] + acc[nt][2] + acc[nt][3];
        cp += __shfl_xor(cp, 16, 64);
        cp += __shfl_xor(cp, 32, 64);
        if (quad == 0) atomicAdd(&S[ch0 + nt * 16 + n16], cp);
    }
}

// ---------------- K2: per-row stats + compact winners + out0 ----------------
__global__ __launch_bounds__(256) void k_stats(
        const int* __restrict__ rowcnt, const int* __restrict__ slots,
        const int* __restrict__ cols,
        const float* __restrict__ s1, const float* __restrict__ s2,
        const float* __restrict__ S, const float* __restrict__ Wh,
        float* __restrict__ out0, float* __restrict__ bsum,
        int* __restrict__ gnw, int* __restrict__ gcol, float* __restrict__ gws) {
    __shared__ float eh[HEADS][CAP];           // per-head e values (all slots)
    __shared__ int   kk[CAP];                  // edge ids
    __shared__ int   cc[CAP];                  // edge cols
    __shared__ int   wcol[CAP];                // winner cols (compact)
    __shared__ float weh[HEADS][CAP];          // winner e (compact)
    __shared__ float wgt[HEADS][CAP];          // winner weights (compact)
    __shared__ float mh[HEADS], dh[HEADS], bh[HEADS];
    __shared__ int   nw_sh;

    const int i = blockIdx.x;
    const int t = threadIdx.x, head = t >> 6, lane = t & 63;
    int cnt = rowcnt[i];
    if (cnt > CAP) cnt = CAP;
    if (t == 0) nw_sh = 0;

    const float4 s1r = *(const float4*)(s1 + i * HEADS);

    for (int q = t; q < cnt; q += 256) {
        const int k = slots[i * CAP + q];
        const int c = cols[k];
        kk[q] = k; cc[q] = c;
        const float4 s2c = *(const float4*)(s2 + c * HEADS);
        float x;
        x = s1r.x + s2c.x; eh[0][q] = (x > 0.f) ? x : 0.2f * x;
        x = s1r.y + s2c.y; eh[1][q] = (x > 0.f) ? x : 0.2f * x;
        x = s1r.z + s2c.z; eh[2][q] = (x > 0.f) ? x : 0.2f * x;
        x = s1r.w + s2c.w; eh[3][q] = (x > 0.f) ? x : 0.2f * x;
    }
    __syncthreads();

    // dedupe (last-k-wins) + compact winner list
    for (int q = t; q < cnt; q += 256) {
        const int c = cc[q], k = kk[q];
        int win = 1;
        for (int q2 = 0; q2 < cnt; ++q2)
            if (cc[q2] == c && kk[q2] > k) { win = 0; break; }
        if (win) {
            const int pos = atomicAdd(&nw_sh, 1);
            wcol[pos] = c;
            weh[0][pos] = eh[0][q]; weh[1][pos] = eh[1][q];
            weh[2][pos] = eh[2][q]; weh[3][pos] = eh[3][q];
        }
    }
    __syncthreads();
    const int nw = nw_sh;

    // per-head max / exp-sum over winners (wave per head)
    float emax = -1e30f;
    for (int q = lane; q < nw; q += 64) emax = fmaxf(emax, weh[head][q]);
#pragma unroll
    for (int o = 32; o > 0; o >>= 1) emax = fmaxf(emax, __shfl_xor(emax, o, 64));
    const float m = fmaxf(emax, 0.f);   // dense row always has zero background cells

    float ssum = 0.f;
    for (int q = lane; q < nw; q += 64) ssum += __expf(weh[head][q] - m);
#pragma unroll
    for (int o = 32; o > 0; o >>= 1) ssum += __shfl_xor(ssum, o, 64);

    if (lane == 0) {
        const float denom = ssum + (float)(N_NODES - nw) * __expf(-m);
        mh[head] = m;
        dh[head] = denom;
        bh[head] = __expf(-m) / denom;
    }
    __syncthreads();

    // winner weights; export compact list for the attn kernel
    for (int q = t; q < nw; q += 256) {
        const float w0 = __expf(weh[0][q] - mh[0]) / dh[0];
        const float w1 = __expf(weh[1][q] - mh[1]) / dh[1];
        const float w2 = __expf(weh[2][q] - mh[2]) / dh[2];
        const float w3 = __expf(weh[3][q] - mh[3]) / dh[3];
        wgt[0][q] = w0; wgt[1][q] = w1; wgt[2][q] = w2; wgt[3][q] = w3;
        gcol[i * CAP + q] = wcol[q];
        gws[i * CAP + q]  = 0.25f * (w0 + w1 + w2 + w3);
    }
    if (t == 0) {
        gnw[i] = nw;
        bsum[i] = 0.25f * (bh[0] + bh[1] + bh[2] + bh[3]);
    }
    __syncthreads();

    // out0: thread t owns channel t; unconditional loop over compact winners
    const float b_ = bh[head];
    float acc = b_ * S[t];
    for (int q = 0; q < nw; ++q)
        acc += (wgt[head][q] - b_) * Wh[(size_t)wcol[q] * HC + t];
    __builtin_nontemporal_store(fmaxf(acc, 0.f), out0 + (size_t)i * HC + t);
}

// ---------------- K3: attn rows: direct nt fill, barrier, in-place winner overwrite ----------------
// 4 consecutive rows per 1024-thread block -> 64 KB contiguous stream per block.
__global__ __launch_bounds__(1024) void k_attn(
        const float* __restrict__ bsum, const int* __restrict__ gnw,
        const int* __restrict__ gcol, const float* __restrict__ gws,
        float* __restrict__ attn) {
    const int g = threadIdx.x >> 8;            // row group 0..3
    const int t = threadIdx.x & 255;
    const int i = blockIdx.x * 4 + g;
    const float v = bsum[i];
    const int nw = gnw[i];
    const v4f v4 = {v, v, v, v};
    v4f* dst = (v4f*)(attn + (size_t)i * N_NODES);
#pragma unroll
    for (int rep = 0; rep < 4; ++rep)
        __builtin_nontemporal_store(v4, &dst[rep * 256 + t]);
    __syncthreads();   // drains vmcnt: background stores ordered at L2 before overwrites
    for (int q = t; q < nw; q += 256)
        attn[(size_t)i * N_NODES + gcol[i * CAP + q]] = gws[i * CAP + q];
}

extern "C" void kernel_launch(void* const* d_in, const int* in_sizes, int n_in,
                              void* d_out, int out_size, void* d_ws, size_t ws_size,
                              hipStream_t stream) {
    const float* h  = (const float*)d_in[0];
    const int*   ei = (const int*)d_in[1];
    const float* W  = (const float*)d_in[2];
    const float* a  = (const float*)d_in[3];
    const int* rows = ei;
    const int* cols = ei + E_EDGES;

    float* out0 = (float*)d_out;
    float* attn = out0 + (size_t)N_NODES * HC;

    char* p = (char*)d_ws;
    auto carve = [&](size_t bytes) { char* q = p; p += (bytes + 255) & ~(size_t)255; return q; };
    float* S       = (float*)carve(sizeof(float) * HC);
    int*   rowcnt  = (int*)carve(sizeof(int) * N_NODES);
    float* Wh      = (float*)carve(sizeof(float) * (size_t)N_NODES * HC);
    float* s1      = (float*)carve(sizeof(float) * N_NODES * HEADS);
    float* s2      = (float*)carve(sizeof(float) * N_NODES * HEADS);
    float* bsum    = (float*)carve(sizeof(float) * N_NODES);
    int*   slots   = (int*)carve(sizeof(int) * (size_t)N_NODES * CAP);
    int*   gnw     = (int*)carve(sizeof(int) * N_NODES);
    int*   gcol    = (int*)carve(sizeof(int) * (size_t)N_NODES * CAP);
    float* gws     = (float*)carve(sizeof(float) * (size_t)N_NODES * CAP);
    unsigned short* h_hi = (unsigned short*)carve(sizeof(short) * (size_t)N_NODES * IN_F);
    unsigned short* h_lo = (unsigned short*)carve(sizeof(short) * (size_t)N_NODES * IN_F);
    unsigned short* W_hi = (unsigned short*)carve(sizeof(short) * HC * IN_F);
    unsigned short* W_lo = (unsigned short*)carve(sizeof(short) * HC * IN_F);

    k_prep<<<(N_NODES * IN_F + HC * IN_F) / 4 / 256, 256, 0, stream>>>(
        h, W, h_hi, h_lo, W_hi, W_lo, rowcnt, S);
    k_linear_mfma<<<N_NODES / 16, 256, 0, stream>>>(h_hi, h_lo, W_hi, W_lo, a, rows,
                                                    rowcnt, slots, Wh, s1, s2, S);
    k_stats<<<N_NODES, 256, 0, stream>>>(rowcnt, slots, cols, s1, s2, S, Wh,
                                         out0, bsum, gnw, gcol, gws);
    k_attn<<<N_NODES / 4, 1024, 0, stream>>>(bsum, gnw, gcol, gws, attn);
}

// Round 10
// 142.925 us; speedup vs baseline: 1.0464x; 1.0464x over previous
//
#include <hip/hip_runtime.h>

#define N_NODES 4096
#define E_EDGES 131072
#define IN_F    256
#define OUT_F   64
#define HEADS   4
#define HC      256        // HEADS*OUT_F
#define CAP     128        // per-row slot capacity (fixed dataset degree: mean 32, max ~54)

typedef float v4f __attribute__((ext_vector_type(4)));
typedef short v8s __attribute__((ext_vector_type(8)));   // 8 bf16 (4 VGPRs) MFMA A/B fragment
typedef float v4acc __attribute__((ext_vector_type(4))); // MFMA C/D fragment

__device__ __forceinline__ unsigned short bf16_rn(float x) {
    unsigned u = __builtin_bit_cast(unsigned, x);
    unsigned r = (u + 0x7FFFu + ((u >> 16) & 1u)) >> 16;   // round-to-nearest-even
    return (unsigned short)r;
}
__device__ __forceinline__ float bf16_to_f(unsigned short b) {
    unsigned u = ((unsigned)b) << 16;
    return __builtin_bit_cast(float, u);
}

// ---------------- K0: split h,W into bf16 hi/lo (x4 vectorized) + zero rowcnt/S ----------------
__global__ __launch_bounds__(256) void k_prep(
        const float* __restrict__ h, const float* __restrict__ W,
        unsigned short* __restrict__ h_hi, unsigned short* __restrict__ h_lo,
        unsigned short* __restrict__ W_hi, unsigned short* __restrict__ W_lo,
        int* __restrict__ rowcnt, float* __restrict__ S) {
    const int tid = blockIdx.x * 256 + threadIdx.x;
    if (tid < N_NODES) rowcnt[tid] = 0;
    else if (tid < N_NODES + HC) S[tid - N_NODES] = 0.f;

    const int HN4 = (N_NODES * IN_F) / 4;     // 262144
    const float4* src;
    unsigned short *dhi, *dlo;
    int j;
    if (tid < HN4) { src = (const float4*)h; dhi = h_hi; dlo = h_lo; j = tid; }
    else           { src = (const float4*)W; dhi = W_hi; dlo = W_lo; j = tid - HN4; }
    const float4 x = src[j];
    const unsigned short hx = bf16_rn(x.x), hy = bf16_rn(x.y), hz = bf16_rn(x.z), hw = bf16_rn(x.w);
    ushort4 hi4 = make_ushort4(hx, hy, hz, hw);
    ushort4 lo4 = make_ushort4(bf16_rn(x.x - bf16_to_f(hx)), bf16_rn(x.y - bf16_to_f(hy)),
                               bf16_rn(x.z - bf16_to_f(hz)), bf16_rn(x.w - bf16_to_f(hw)));
    *(ushort4*)(dhi + j * 4) = hi4;
    *(ushort4*)(dlo + j * 4) = lo4;
}

// ---------------- K1: edge append + Wh = h @ W^T via split bf16 MFMA + s1/s2/colsum ----------------
__global__ __launch_bounds__(256) void k_linear_mfma(
        const unsigned short* __restrict__ h_hi, const unsigned short* __restrict__ h_lo,
        const unsigned short* __restrict__ W_hi, const unsigned short* __restrict__ W_lo,
        const float* __restrict__ a, const int* __restrict__ rows,
        int* __restrict__ rowcnt, int* __restrict__ slots,
        float* __restrict__ Wh, float* __restrict__ s1, float* __restrict__ s2,
        float* __restrict__ S) {
    const int t = threadIdx.x;

    // --- edge append (independent of MFMA dataflow; hides under A/B load latency) ---
    {
        const int e0 = blockIdx.x * 512 + t;
#pragma unroll
        for (int rep = 0; rep < 2; ++rep) {
            const int k = e0 + rep * 256;
            const int r = rows[k];
            const int pos = atomicAdd(&rowcnt[r], 1);
            if (pos < CAP) slots[r * CAP + pos] = k;
        }
    }

    const int wave = t >> 6, lane = t & 63;
    const int n16 = lane & 15, quad = lane >> 4;
    const int node0 = blockIdx.x * 16;
    const int ch0 = wave * 64;
    const int head = wave;

    v4acc acc[4];
#pragma unroll
    for (int nt = 0; nt < 4; ++nt) acc[nt] = (v4acc){0.f, 0.f, 0.f, 0.f};

    const int arow = (node0 + n16) * IN_F;
#pragma unroll
    for (int s = 0; s < 8; ++s) {                       // K = 256 in steps of 32
        const int k0 = s * 32 + quad * 8;
        v8s Ah = *(const v8s*)(h_hi + arow + k0);
        v8s Al = *(const v8s*)(h_lo + arow + k0);
#pragma unroll
        for (int nt = 0; nt < 4; ++nt) {
            const int ch = ch0 + nt * 16 + n16;
            v8s Bh = *(const v8s*)(W_hi + ch * IN_F + k0);
            v8s Bl = *(const v8s*)(W_lo + ch * IN_F + k0);
            acc[nt] = __builtin_amdgcn_mfma_f32_16x16x32_bf16(Ah, Bh, acc[nt], 0, 0, 0);
            acc[nt] = __builtin_amdgcn_mfma_f32_16x16x32_bf16(Ah, Bl, acc[nt], 0, 0, 0);
            acc[nt] = __builtin_amdgcn_mfma_f32_16x16x32_bf16(Al, Bh, acc[nt], 0, 0, 0);
        }
    }

#pragma unroll
    for (int nt = 0; nt < 4; ++nt) {
        const int ch = ch0 + nt * 16 + n16;
#pragma unroll
        for (int r = 0; r < 4; ++r)
            Wh[(size_t)(node0 + quad * 4 + r) * HC + ch] = acc[nt][r];
    }

    float a1v[4], a2v[4];
#pragma unroll
    for (int nt = 0; nt < 4; ++nt) {
        a1v[nt] = a[head * 2 * OUT_F + nt * 16 + n16];
        a2v[nt] = a[head * 2 * OUT_F + OUT_F + nt * 16 + n16];
    }
#pragma unroll
    for (int r = 0; r < 4; ++r) {
        float p1 = acc[0][r] * a1v[0] + acc[1][r] * a1v[1] + acc[2][r] * a1v[2] + acc[3][r] * a1v[3];
        float p2 = acc[0][r] * a2v[0] + acc[1][r] * a2v[1] + acc[2][r] * a2v[2] + acc[3][r] * a2v[3];
#pragma unroll
        for (int o = 1; o < 16; o <<= 1) {
            p1 += __shfl_xor(p1, o, 64);
            p2 += __shfl_xor(p2, o, 64);
        }
        if (n16 == 0) {
            const int node = node0 + quad * 4 + r;
            s1[node * HEADS + head] = p1;
            s2[node * HEADS + head] = p2;
        }
    }

#pragma unroll
    for (int nt = 0; nt < 4; ++nt) {
        float cp = acc[nt][0] + acc[nt][1] + acc[nt][2] + acc[nt][3];
        cp += __shfl_xor(cp, 16, 64);
        cp += __shfl_xor(cp, 32, 64);
        if (quad == 0) atomicAdd(&S[ch0 + nt * 16 + n16], cp);
    }
}

// ---------------- K2: per-row stats + compact winners + out0 ----------------
__global__ __launch_bounds__(256) void k_stats(
        const int* __restrict__ rowcnt, const int* __restrict__ slots,
        const int* __restrict__ cols,
        const float* __restrict__ s1, const float* __restrict__ s2,
        const float* __restrict__ S, const float* __restrict__ Wh,
        float* __restrict__ out0, float* __restrict__ bsum,
        int* __restrict__ gnw, int* __restrict__ gcol, float* __restrict__ gws) {
    __shared__ float eh[HEADS][CAP];           // per-head e values (all slots)
    __shared__ int   kk[CAP];                  // edge ids
    __shared__ int   cc[CAP];                  // edge cols
    __shared__ int   wcol[CAP];                // winner cols (compact)
    __shared__ float weh[HEADS][CAP];          // winner e (compact)
    __shared__ float wgt[HEADS][CAP];          // winner weights (compact)
    __shared__ float mh[HEADS], dh[HEADS], bh[HEADS];
    __shared__ int   nw_sh;

    const int i = blockIdx.x;
    const int t = threadIdx.x, head = t >> 6, lane = t & 63;
    int cnt = rowcnt[i];
    if (cnt > CAP) cnt = CAP;
    if (t == 0) nw_sh = 0;

    const float4 s1r = *(const float4*)(s1 + i * HEADS);

    for (int q = t; q < cnt; q += 256) {
        const int k = slots[i * CAP + q];
        const int c = cols[k];
        kk[q] = k; cc[q] = c;
        const float4 s2c = *(const float4*)(s2 + c * HEADS);
        float x;
        x = s1r.x + s2c.x; eh[0][q] = (x > 0.f) ? x : 0.2f * x;
        x = s1r.y + s2c.y; eh[1][q] = (x > 0.f) ? x : 0.2f * x;
        x = s1r.z + s2c.z; eh[2][q] = (x > 0.f) ? x : 0.2f * x;
        x = s1r.w + s2c.w; eh[3][q] = (x > 0.f) ? x : 0.2f * x;
    }
    __syncthreads();

    // dedupe (last-k-wins) + compact winner list
    for (int q = t; q < cnt; q += 256) {
        const int c = cc[q], k = kk[q];
        int win = 1;
        for (int q2 = 0; q2 < cnt; ++q2)
            if (cc[q2] == c && kk[q2] > k) { win = 0; break; }
        if (win) {
            const int pos = atomicAdd(&nw_sh, 1);
            wcol[pos] = c;
            weh[0][pos] = eh[0][q]; weh[1][pos] = eh[1][q];
            weh[2][pos] = eh[2][q]; weh[3][pos] = eh[3][q];
        }
    }
    __syncthreads();
    const int nw = nw_sh;

    // per-head max / exp-sum over winners (wave per head)
    float emax = -1e30f;
    for (int q = lane; q < nw; q += 64) emax = fmaxf(emax, weh[head][q]);
#pragma unroll
    for (int o = 32; o > 0; o >>= 1) emax = fmaxf(emax, __shfl_xor(emax, o, 64));
    const float m = fmaxf(emax, 0.f);   // dense row always has zero background cells

    float ssum = 0.f;
    for (int q = lane; q < nw; q += 64) ssum += __expf(weh[head][q] - m);
#pragma unroll
    for (int o = 32; o > 0; o >>= 1) ssum += __shfl_xor(ssum, o, 64);

    if (lane == 0) {
        const float denom = ssum + (float)(N_NODES - nw) * __expf(-m);
        mh[head] = m;
        dh[head] = denom;
        bh[head] = __expf(-m) / denom;
    }
    __syncthreads();

    // winner weights; export compact list for the attn kernel
    for (int q = t; q < nw; q += 256) {
        const float w0 = __expf(weh[0][q] - mh[0]) / dh[0];
        const float w1 = __expf(weh[1][q] - mh[1]) / dh[1];
        const float w2 = __expf(weh[2][q] - mh[2]) / dh[2];
        const float w3 = __expf(weh[3][q] - mh[3]) / dh[3];
        wgt[0][q] = w0; wgt[1][q] = w1; wgt[2][q] = w2; wgt[3][q] = w3;
        gcol[i * CAP + q] = wcol[q];
        gws[i * CAP + q]  = 0.25f * (w0 + w1 + w2 + w3);
    }
    if (t == 0) {
        gnw[i] = nw;
        bsum[i] = 0.25f * (bh[0] + bh[1] + bh[2] + bh[3]);
    }
    __syncthreads();

    // out0: thread t owns channel t; unconditional loop over compact winners
    const float b_ = bh[head];
    float acc = b_ * S[t];
    for (int q = 0; q < nw; ++q)
        acc += (wgt[head][q] - b_) * Wh[(size_t)wcol[q] * HC + t];
    __builtin_nontemporal_store(fmaxf(acc, 0.f), out0 + (size_t)i * HC + t);
}

// ---------------- K3: attn row = background + winner merge (LDS), one store pass ----------------
__global__ __launch_bounds__(256) void k_attn(
        const float* __restrict__ bsum, const int* __restrict__ gnw,
        const int* __restrict__ gcol, const float* __restrict__ gws,
        float* __restrict__ attn) {
    __shared__ float rowbuf[N_NODES];          // 16 KB
    const int i = blockIdx.x, t = threadIdx.x;
    const float v = bsum[i];
    const int nw = gnw[i];
    const float4 v4 = make_float4(v, v, v, v);
    float4* rb4 = (float4*)rowbuf;
#pragma unroll
    for (int rep = 0; rep < 4; ++rep) rb4[rep * 256 + t] = v4;
    __syncthreads();
    for (int q = t; q < nw; q += 256) rowbuf[gcol[i * CAP + q]] = gws[i * CAP + q];
    __syncthreads();
    const v4f* src = (const v4f*)rowbuf;
    v4f* dst = (v4f*)(attn + (size_t)i * N_NODES);
#pragma unroll
    for (int rep = 0; rep < 4; ++rep)
        __builtin_nontemporal_store(src[rep * 256 + t], &dst[rep * 256 + t]);
}

extern "C" void kernel_launch(void* const* d_in, const int* in_sizes, int n_in,
                              void* d_out, int out_size, void* d_ws, size_t ws_size,
                              hipStream_t stream) {
    const float* h  = (const float*)d_in[0];
    const int*   ei = (const int*)d_in[1];
    const float* W  = (const float*)d_in[2];
    const float* a  = (const float*)d_in[3];
    const int* rows = ei;
    const int* cols = ei + E_EDGES;

    float* out0 = (float*)d_out;
    float* attn = out0 + (size_t)N_NODES * HC;

    char* p = (char*)d_ws;
    auto carve = [&](size_t bytes) { char* q = p; p += (bytes + 255) & ~(size_t)255; return q; };
    float* S       = (float*)carve(sizeof(float) * HC);
    int*   rowcnt  = (int*)carve(sizeof(int) * N_NODES);
    float* Wh      = (float*)carve(sizeof(float) * (size_t)N_NODES * HC);
    float* s1      = (float*)carve(sizeof(float) * N_NODES * HEADS);
    float* s2      = (float*)carve(sizeof(float) * N_NODES * HEADS);
    float* bsum    = (float*)carve(sizeof(float) * N_NODES);
    int*   slots   = (int*)carve(sizeof(int) * (size_t)N_NODES * CAP);
    int*   gnw     = (int*)carve(sizeof(int) * N_NODES);
    int*   gcol    = (int*)carve(sizeof(int) * (size_t)N_NODES * CAP);
    float* gws     = (float*)carve(sizeof(float) * (size_t)N_NODES * CAP);
    unsigned short* h_hi = (unsigned short*)carve(sizeof(short) * (size_t)N_NODES * IN_F);
    unsigned short* h_lo = (unsigned short*)carve(sizeof(short) * (size_t)N_NODES * IN_F);
    unsigned short* W_hi = (unsigned short*)carve(sizeof(short) * HC * IN_F);
    unsigned short* W_lo = (unsigned short*)carve(sizeof(short) * HC * IN_F);

    k_prep<<<(N_NODES * IN_F + HC * IN_F) / 4 / 256, 256, 0, stream>>>(
        h, W, h_hi, h_lo, W_hi, W_lo, rowcnt, S);
    k_linear_mfma<<<N_NODES / 16, 256, 0, stream>>>(h_hi, h_lo, W_hi, W_lo, a, rows,
                                                    rowcnt, slots, Wh, s1, s2, S);
    k_stats<<<N_NODES, 256, 0, stream>>>(rowcnt, slots, cols, s1, s2, S, Wh,
                                         out0, bsum, gnw, gcol, gws);
    k_attn<<<N_NODES, 256, 0, stream>>>(bsum, gnw, gcol, gws, attn);
}